// Round 3
// baseline (218.899 us; speedup 1.0000x reference)
//
#include <hip/hip_runtime.h>

// Problem constants (fixed by setup_inputs)
#define BB   4        // batch
#define SS   2048     // sequence
#define DD   768      // hidden
#define NN   4096     // spans
#define PW   20       // pos/width table width
#define CH   16       // cumsum chunk length
#define NCH  128      // SS / CH
#define ROW  2364     // output row length: 3*768 + 3*20
#define DQ   192      // DD / 4  (f4 columns per row)

// clang-native 4-float vector: accepted by __builtin_nontemporal_store,
// emits global_load/store_dwordx4.
typedef float f4 __attribute__((ext_vector_type(4)));

// Kernel 1: per-chunk partial sums along S, f4-vectorized.
// grid 384 x 256 threads = BB*NCH*DQ lanes; thread = (b, chunk c, f4-col q).
__global__ __launch_bounds__(256) void partial_kernel(const float* __restrict__ x,
                                                      float* __restrict__ partial) {
    int tid = blockIdx.x * 256 + threadIdx.x;     // 0 .. BB*NCH*DQ-1
    int b = tid / (NCH * DQ);
    int r = tid - b * (NCH * DQ);
    int c = r / DQ;
    int q = r - c * DQ;
    const f4* xp = (const f4*)x + ((size_t)(b * SS + c * CH)) * DQ + q;
    f4 s = {0.f, 0.f, 0.f, 0.f};
#pragma unroll
    for (int i = 0; i < CH; ++i) s += xp[(size_t)i * DQ];
    ((f4*)partial)[((size_t)(b * NCH + c)) * DQ + q] = s;
}

// Kernel 2: exclusive prefix over the NCH chunk sums of each (b,d) column.
// grid 12 blocks x 256 = 3072 threads = BB*DD.  (scalar; tiny kernel)
__global__ __launch_bounds__(256) void prefix_kernel(float* __restrict__ partial) {
    int t = blockIdx.x * 256 + threadIdx.x;   // 0..3071
    int b = t / DD;
    int d = t - b * DD;
    float* p = partial + (size_t)b * NCH * DD + d;
    float v[NCH];
#pragma unroll
    for (int c = 0; c < NCH; ++c) v[c] = p[(size_t)c * DD];
    float run = 0.f;
#pragma unroll
    for (int c = 0; c < NCH; ++c) { float nv = run + v[c]; p[(size_t)c * DD] = run; run = nv; }
}

// Kernel 3: inclusive cumsum cs[b, s+1, :]; cs[b,0,:] = 0.  f4-vectorized.
// Same decomposition as kernel 1.
__global__ __launch_bounds__(256) void cumsum_kernel(const float* __restrict__ x,
                                                     const float* __restrict__ partial,
                                                     float* __restrict__ cs) {
    int tid = blockIdx.x * 256 + threadIdx.x;
    int b = tid / (NCH * DQ);
    int r = tid - b * (NCH * DQ);
    int c = r / DQ;
    int q = r - c * DQ;
    f4 run = ((const f4*)partial)[((size_t)(b * NCH + c)) * DQ + q];
    const f4* xp = (const f4*)x + ((size_t)(b * SS + c * CH)) * DQ + q;
    f4*       cp = (f4*)cs + ((size_t)(b * (SS + 1) + c * CH + 1)) * DQ + q;
    if (c == 0) {
        f4 z = {0.f, 0.f, 0.f, 0.f};
        ((f4*)cs)[((size_t)(b * (SS + 1))) * DQ + q] = z;
    }
    f4 v[CH];
#pragma unroll
    for (int i = 0; i < CH; ++i) v[i] = xp[(size_t)i * DQ];
#pragma unroll
    for (int i = 0; i < CH; ++i) { run += v[i]; cp[(size_t)i * DQ] = run; }
}

// Kernel 4: assemble output rows.  grid (NN), block 192 — one block handles
// all BB batches of its span: span decode / bucket / table rows done once,
// and 16 independent f4 row-loads in flight per thread (MLP vs L3 latency).
// Row layout (f4 indices): mean [0,192) | xs0 [192,384) | pos0 [384,389)
//                          | xs1 [389,581) | pos1 [581,586) | wemb [586,591)
// out is write-once -> all stores non-temporal (don't evict cs/x from L2/L3).
__global__ __launch_bounds__(192) void gather_kernel(const float* __restrict__ x,
                                                     const int* __restrict__ spans,
                                                     const int* __restrict__ pt_labels,
                                                     const float* __restrict__ wtab,
                                                     const float* __restrict__ ptab,
                                                     const float* __restrict__ cs,
                                                     float* __restrict__ out) {
    int n = blockIdx.x;
    int t = threadIdx.x;   // 0..191

    int s0 = spans[2 * n];
    int s1 = spans[2 * n + 1];
    int width = s1 - s0 + 1;
    float inv_w = 1.0f / (float)width;

    // em = searchsorted(BUCKET_BINS, width, 'right') - 1; width >= 1 always.
    const int bins[15] = {1, 2, 3, 4, 5, 7, 8, 9, 10, 15, 16, 31, 32, 63, 64};
    int em = 0;
#pragma unroll
    for (int i = 0; i < 15; ++i) em += (width >= bins[i]) ? 1 : 0;

    // Issue all 16 row-fragment loads (4 per batch) before any compute/store.
    f4 a[BB], c0[BB], v0[BB], v1[BB];
#pragma unroll
    for (int b = 0; b < BB; ++b) {
        const f4* cs0 = (const f4*)cs + ((size_t)(b * (SS + 1) + s0)) * DQ;
        const f4* cs1 = (const f4*)cs + ((size_t)(b * (SS + 1) + s1 + 1)) * DQ;
        const f4* x0  = (const f4*)x  + ((size_t)(b * SS + s0)) * DQ;
        const f4* x1  = (const f4*)x  + ((size_t)(b * SS + s1)) * DQ;
        a[b]  = cs1[t];
        c0[b] = cs0[t];
        v0[b] = x0[t];
        v1[b] = x1[t];
    }
#pragma unroll
    for (int b = 0; b < BB; ++b) {
        f4* o = (f4*)(out + ((size_t)(b * NN) + n) * ROW);
        f4 m = (a[b] - c0[b]) * inv_w;
        __builtin_nontemporal_store(m,     o + t);
        __builtin_nontemporal_store(v0[b], o + 192 + t);
        __builtin_nontemporal_store(v1[b], o + 389 + t);
    }

    // Small broadcast embeddings: lanes 0..14, table f4 loaded once,
    // stored to all 4 batch rows.
    if (t < 15) {
        f4 e;
        int slot;
        if (t < 5) {
            int l0 = pt_labels[s0];
            e = ((const f4*)(ptab + l0 * PW))[t];
            slot = 384 + t;
        } else if (t < 10) {
            int l1 = pt_labels[s1];
            e = ((const f4*)(ptab + l1 * PW))[t - 5];
            slot = 581 + (t - 5);
        } else {
            e = ((const f4*)(wtab + em * PW))[t - 10];
            slot = 586 + (t - 10);
        }
#pragma unroll
        for (int b = 0; b < BB; ++b) {
            f4* o = (f4*)(out + ((size_t)(b * NN) + n) * ROW);
            __builtin_nontemporal_store(e, o + slot);
        }
    }
}

extern "C" void kernel_launch(void* const* d_in, const int* in_sizes, int n_in,
                              void* d_out, int out_size, void* d_ws, size_t ws_size,
                              hipStream_t stream) {
    const float* x     = (const float*)d_in[0];
    const int*   spans = (const int*)d_in[1];
    const int*   pt    = (const int*)d_in[2];
    const float* wtab  = (const float*)d_in[3];
    const float* ptab  = (const float*)d_in[4];
    float* out = (float*)d_out;

    float* cs      = (float*)d_ws;                         // BB*(SS+1)*DD floats ~25.2 MB
    float* partial = cs + (size_t)BB * (SS + 1) * DD;      // BB*NCH*DD floats ~1.6 MB

    const int NB = (BB * NCH * DQ) / 256;                  // 384 blocks
    partial_kernel<<<NB, 256, 0, stream>>>(x, partial);
    prefix_kernel<<<12, 256, 0, stream>>>(partial);
    cumsum_kernel<<<NB, 256, 0, stream>>>(x, partial, cs);
    gather_kernel<<<NN, 192, 0, stream>>>(x, spans, pt, wtab, ptab, cs, out);
}

// Round 5
// 211.136 us; speedup vs baseline: 1.0368x; 1.0368x over previous
//
#include <hip/hip_runtime.h>

// Problem constants (fixed by setup_inputs)
#define BB   4        // batch
#define SS   2048     // sequence
#define DD   768      // hidden
#define NN   4096     // spans
#define PW   20       // pos/width table width
#define CH   16       // cumsum chunk length
#define NCH  128      // SS / CH
#define ROW  2364     // output row length: 3*768 + 3*20
#define DQ   192      // DD / 4  (f4 columns per row)

// clang-native 4-float vector (same codegen as float4: global_*_dwordx4).
typedef float f4 __attribute__((ext_vector_type(4)));

// Kernel 1: per-chunk partial sums along S, f4-vectorized.
// grid 384 x 256 threads = BB*NCH*DQ lanes; thread = (b, chunk c, f4-col q).
__global__ __launch_bounds__(256) void partial_kernel(const float* __restrict__ x,
                                                      float* __restrict__ partial) {
    int tid = blockIdx.x * 256 + threadIdx.x;     // 0 .. BB*NCH*DQ-1
    int b = tid / (NCH * DQ);
    int r = tid - b * (NCH * DQ);
    int c = r / DQ;
    int q = r - c * DQ;
    const f4* xp = (const f4*)x + ((size_t)(b * SS + c * CH)) * DQ + q;
    f4 s = {0.f, 0.f, 0.f, 0.f};
#pragma unroll
    for (int i = 0; i < CH; ++i) s += xp[(size_t)i * DQ];
    ((f4*)partial)[((size_t)(b * NCH + c)) * DQ + q] = s;
}

// Kernel 2: exclusive prefix over the NCH chunk sums of each (b,d) column.
// grid 12 blocks x 256 = 3072 threads = BB*DD.
// Blocked scan: 4 bursts of 32 loads -> 32 VGPR live, NO scratch spill
// (a flat v[128] array spills; that was a round-1 regression).
__global__ __launch_bounds__(256) void prefix_kernel(float* __restrict__ partial) {
    int t = blockIdx.x * 256 + threadIdx.x;   // 0..3071
    int b = t / DD;
    int d = t - b * DD;
    float* p = partial + (size_t)b * NCH * DD + d;
    float run = 0.f;
#pragma unroll
    for (int blk = 0; blk < NCH / 32; ++blk) {
        float v[32];
#pragma unroll
        for (int c = 0; c < 32; ++c) v[c] = p[(size_t)(blk * 32 + c) * DD];
#pragma unroll
        for (int c = 0; c < 32; ++c) {
            float nv = run + v[c];
            p[(size_t)(blk * 32 + c) * DD] = run;
            run = nv;
        }
    }
}

// Kernel 3: inclusive cumsum cs[b, s+1, :]; cs[b,0,:] = 0.  f4-vectorized,
// CH=16 fully unrolled -> 16 independent dwordx4 loads in flight per thread.
__global__ __launch_bounds__(256) void cumsum_kernel(const float* __restrict__ x,
                                                     const float* __restrict__ partial,
                                                     float* __restrict__ cs) {
    int tid = blockIdx.x * 256 + threadIdx.x;
    int b = tid / (NCH * DQ);
    int r = tid - b * (NCH * DQ);
    int c = r / DQ;
    int q = r - c * DQ;
    f4 run = ((const f4*)partial)[((size_t)(b * NCH + c)) * DQ + q];
    const f4* xp = (const f4*)x + ((size_t)(b * SS + c * CH)) * DQ + q;
    f4*       cp = (f4*)cs + ((size_t)(b * (SS + 1) + c * CH + 1)) * DQ + q;
    if (c == 0) {
        f4 z = {0.f, 0.f, 0.f, 0.f};
        ((f4*)cs)[((size_t)(b * (SS + 1))) * DQ + q] = z;
    }
    f4 v[CH];
#pragma unroll
    for (int i = 0; i < CH; ++i) v[i] = xp[(size_t)i * DQ];
#pragma unroll
    for (int i = 0; i < CH; ++i) { run += v[i]; cp[(size_t)i * DQ] = run; }
}

// Kernel 4: assemble output rows. grid (NN, BB), block 256 — the round-0
// best-measured structure: plain (cached) stores, one batch per block.
// Row layout (f4 indices): mean [0,192) | xs0 [192,384) | pos0 [384,389)
//                          | xs1 [389,581) | pos1 [581,586) | wemb [586,591)
// cs and x are L2/L3-resident from the cumsum pass in the same window, so
// the random row reads mostly hit cache; plain stores let L2 merge the
// 16B-aligned (not 64B-aligned) row-boundary partial lines, which nt
// stores could not (nt was a measured regression: 210.3 -> 213.6/218.9).
__global__ __launch_bounds__(256) void gather_kernel(const float* __restrict__ x,
                                                     const int* __restrict__ spans,
                                                     const int* __restrict__ pt_labels,
                                                     const float* __restrict__ wtab,
                                                     const float* __restrict__ ptab,
                                                     const float* __restrict__ cs,
                                                     float* __restrict__ out) {
    int n = blockIdx.x;
    int b = blockIdx.y;
    int t = threadIdx.x;

    int s0 = spans[2 * n];
    int s1 = spans[2 * n + 1];
    int width = s1 - s0 + 1;
    float inv_w = 1.0f / (float)width;

    // em = searchsorted(BUCKET_BINS, width, 'right') - 1; width >= 1 always.
    const int bins[15] = {1, 2, 3, 4, 5, 7, 8, 9, 10, 15, 16, 31, 32, 63, 64};
    int em = 0;
#pragma unroll
    for (int i = 0; i < 15; ++i) em += (width >= bins[i]) ? 1 : 0;

    const f4* cs0 = (const f4*)cs + ((size_t)(b * (SS + 1) + s0)) * DQ;
    const f4* cs1 = (const f4*)cs + ((size_t)(b * (SS + 1) + s1 + 1)) * DQ;
    const f4* x0  = (const f4*)x  + ((size_t)(b * SS + s0)) * DQ;
    const f4* x1  = (const f4*)x  + ((size_t)(b * SS + s1)) * DQ;
    f4* o = (f4*)(out + ((size_t)(b * NN) + n) * ROW);

    if (t < 192) {
        f4 a  = cs1[t];
        f4 c0 = cs0[t];
        f4 v0 = x0[t];
        f4 v1 = x1[t];
        f4 m = (a - c0) * inv_w;
        o[t]       = m;
        o[192 + t] = v0;
        o[389 + t] = v1;
    } else {
        int u = t - 192;
        if (u < 5) {
            int l0 = pt_labels[s0];
            o[384 + u] = ((const f4*)(ptab + l0 * PW))[u];
        } else if (u < 10) {
            int l1 = pt_labels[s1];
            o[581 + (u - 5)] = ((const f4*)(ptab + l1 * PW))[u - 5];
        } else if (u < 15) {
            o[586 + (u - 10)] = ((const f4*)(wtab + em * PW))[u - 10];
        }
    }
}

extern "C" void kernel_launch(void* const* d_in, const int* in_sizes, int n_in,
                              void* d_out, int out_size, void* d_ws, size_t ws_size,
                              hipStream_t stream) {
    const float* x     = (const float*)d_in[0];
    const int*   spans = (const int*)d_in[1];
    const int*   pt    = (const int*)d_in[2];
    const float* wtab  = (const float*)d_in[3];
    const float* ptab  = (const float*)d_in[4];
    float* out = (float*)d_out;

    float* cs      = (float*)d_ws;                         // BB*(SS+1)*DD floats ~25.2 MB
    float* partial = cs + (size_t)BB * (SS + 1) * DD;      // BB*NCH*DD floats ~1.6 MB

    const int NB = (BB * NCH * DQ) / 256;                  // 384 blocks
    partial_kernel<<<NB, 256, 0, stream>>>(x, partial);
    prefix_kernel<<<12, 256, 0, stream>>>(partial);
    cumsum_kernel<<<NB, 256, 0, stream>>>(x, partial, cs);
    gather_kernel<<<dim3(NN, BB), 256, 0, stream>>>(x, spans, pt, wtab, ptab, cs, out);
}